// Round 9
// baseline (1792.976 us; speedup 1.0000x reference)
//
#include <hip/hip_runtime.h>

#define IN_C  128
#define HID_C 128
#define OUT_C 64
#define NPB      128      // nodes per bucket (pow2)
#define NPB_SH   7
#define NPB_MASK 127
#define MAXB     2048     // max buckets in LDS fast path (N <= 262144)
#define B1_CHUNK 8192     // edges per pass-1 block

typedef __attribute__((ext_vector_type(8))) short short8;
typedef __attribute__((ext_vector_type(4))) float f32x4;

__device__ __forceinline__ unsigned short f2bf(float f) {
    unsigned u = __float_as_uint(f);
    unsigned r = (u + 0x7FFFu + ((u >> 16) & 1u)) >> 16;
    return (unsigned short)r;
}
__device__ __forceinline__ float bf_lo(unsigned u) { return __uint_as_float(u << 16); }
__device__ __forceinline__ float bf_hi(unsigned u) { return __uint_as_float(u & 0xFFFF0000u); }
__device__ __forceinline__ float bfu(unsigned short u) { return __uint_as_float(((unsigned)u) << 16); }

// ---- edge bucketing --------------------------------------------------------

__global__ __launch_bounds__(256) void hist_kernel(const int* __restrict__ dst,
                                                   int* __restrict__ bhist,
                                                   int E, int B) {
    __shared__ int lh[MAXB];
    int t = threadIdx.x;
    int e0 = blockIdx.x * B1_CHUNK;
    int nE = min(B1_CHUNK, E - e0);
    if (B <= MAXB) {
        for (int i = t; i < B; i += 256) lh[i] = 0;
        __syncthreads();
        for (int i = t; i < nE; i += 256) atomicAdd(&lh[dst[e0 + i] >> NPB_SH], 1);
        __syncthreads();
        for (int i = t; i < B; i += 256)
            if (lh[i]) atomicAdd(&bhist[i], lh[i]);
    } else {
        for (int i = t; i < nE; i += 256) atomicAdd(&bhist[dst[e0 + i] >> NPB_SH], 1);
    }
}

__global__ __launch_bounds__(1024) void scan_bucket_kernel(const int* __restrict__ bhist,
                                                           int* __restrict__ bbase,
                                                           int* __restrict__ bcur, int B) {
    __shared__ int sums[1024];
    int t = threadIdx.x;
    int chunk = (B + 1023) >> 10;
    int beg = t * chunk, end = min(beg + chunk, B);
    int s = 0;
    for (int i = beg; i < end; ++i) s += bhist[i];
    sums[t] = s;
    __syncthreads();
    for (int off = 1; off < 1024; off <<= 1) {
        int v = (t >= off) ? sums[t - off] : 0;
        __syncthreads();
        sums[t] += v;
        __syncthreads();
    }
    int run = (t == 0) ? 0 : sums[t - 1];
    for (int i = beg; i < end; ++i) {
        bbase[i] = run; bcur[i] = run;
        run += bhist[i];
    }
    if (t == 1023) bbase[B] = sums[1023];
}

__global__ __launch_bounds__(256) void bucket_kernel(const int* __restrict__ src,
                                                     const int* __restrict__ dst,
                                                     int* __restrict__ bcur,
                                                     int* __restrict__ ebuf,
                                                     int E, int B) {
    __shared__ int hist[MAXB];
    __shared__ int runb[MAXB];
    int t = threadIdx.x;
    int e0 = blockIdx.x * B1_CHUNK;
    int nE = min(B1_CHUNK, E - e0);
    if (B <= MAXB) {
        for (int i = t; i < B; i += 256) hist[i] = 0;
        __syncthreads();
        for (int i = t; i < nE; i += 256) atomicAdd(&hist[dst[e0 + i] >> NPB_SH], 1);
        __syncthreads();
        for (int i = t; i < B; i += 256) {
            int c = hist[i];
            runb[i] = c ? atomicAdd(&bcur[i], c) : 0;
            hist[i] = 0;
        }
        __syncthreads();
        for (int i = t; i < nE; i += 256) {
            int d = dst[e0 + i], s = src[e0 + i];
            int b = d >> NPB_SH;
            int off2 = atomicAdd(&hist[b], 1);
            ebuf[runb[b] + off2] = (s << NPB_SH) | (d & NPB_MASK);
        }
    } else {
        for (int i = t; i < nE; i += 256) {
            int d = dst[e0 + i], s = src[e0 + i];
            int pos = atomicAdd(&bcur[d >> NPB_SH], 1);
            ebuf[pos] = (s << NPB_SH) | (d & NPB_MASK);
        }
    }
}

// per-bucket degree -> dinv (no sort/col/rowptr needed anymore)
__global__ __launch_bounds__(256) void dinv_bucket_kernel(const int* __restrict__ ebuf,
                                                          const int* __restrict__ bbase,
                                                          float* __restrict__ dinv, int N) {
    __shared__ int cnt[NPB];
    int b = blockIdx.x, t = threadIdx.x;
    if (t < NPB) cnt[t] = 0;
    __syncthreads();
    int base = bbase[b], size = bbase[b + 1] - base;
    for (int i = t; i < size; i += 256) atomicAdd(&cnt[ebuf[base + i] & NPB_MASK], 1);
    __syncthreads();
    int d = (b << NPB_SH) + t;
    if (t < NPB && d < N) dinv[d] = rsqrtf((float)(cnt[t] + 1));  // +1 self-loop
}

// ---- MFMA dense transform: slab-major bf16 output --------------------------
// Hs slab ct holds channels [ct*16, ct*16+16) for all rows: Hs + ct*slabR*16.

template<int C, typename InT, bool SLABIN>
__global__ __launch_bounds__(256) void mm_mfma_kernel(
    const InT* __restrict__ X, const float* __restrict__ W,
    const float* __restrict__ dinv, unsigned short* __restrict__ Hs,
    int n, size_t slabR) {
    constexpr int LD = 136;
    __shared__ unsigned short Wt[C][LD];
    int t = threadIdx.x;

    for (int i = t; i < (128 * C) / 4; i += 256) {
        int idx = i * 4;
        int k = idx / C, c = idx % C;
        float4 wv = *(const float4*)&W[(size_t)k * C + c];
        Wt[c + 0][k] = f2bf(wv.x);
        Wt[c + 1][k] = f2bf(wv.y);
        Wt[c + 2][k] = f2bf(wv.z);
        Wt[c + 3][k] = f2bf(wv.w);
    }
    __syncthreads();

    int w = t >> 6, lane = t & 63;
    int m = lane & 15, quad = lane >> 4;
    int row0 = blockIdx.x * 64 + w * 16;
    int arow = min(row0 + m, n - 1);

    constexpr int NT = C / 16;
    f32x4 acc[NT];
#pragma unroll
    for (int ct = 0; ct < NT; ++ct) acc[ct] = (f32x4){0.f, 0.f, 0.f, 0.f};

#pragma unroll
    for (int kk = 0; kk < 4; ++kk) {
        int k0 = kk * 32 + quad * 8;
        short8 a;
        if constexpr (sizeof(InT) == 4) {          // fp32 row-major input
            const float* xp = (const float*)X + (size_t)arow * 128 + k0;
            float4 f0 = *(const float4*)xp;
            float4 f1 = *(const float4*)(xp + 4);
            a[0] = (short)f2bf(f0.x); a[1] = (short)f2bf(f0.y);
            a[2] = (short)f2bf(f0.z); a[3] = (short)f2bf(f0.w);
            a[4] = (short)f2bf(f1.x); a[5] = (short)f2bf(f1.y);
            a[6] = (short)f2bf(f1.z); a[7] = (short)f2bf(f1.w);
        } else if constexpr (SLABIN) {             // bf16 slabbed input (16-ch slabs)
            const unsigned short* p = (const unsigned short*)X +
                (size_t)(k0 >> 4) * slabR * 16 + (size_t)arow * 16 + (k0 & 8);
            a = *(const short8*)p;
        } else {                                   // bf16 row-major input
            a = *(const short8*)((const unsigned short*)X + (size_t)arow * 128 + k0);
        }
#pragma unroll
        for (int ct = 0; ct < NT; ++ct) {
            short8 b = *(const short8*)&Wt[ct * 16 + m][k0];
            acc[ct] = __builtin_amdgcn_mfma_f32_16x16x32_bf16(a, b, acc[ct], 0, 0, 0);
        }
    }

    int qrow = row0 + quad * 4;
    float dv[4];
#pragma unroll
    for (int r = 0; r < 4; ++r) dv[r] = (qrow + r < n) ? dinv[qrow + r] : 0.f;
#pragma unroll
    for (int ct = 0; ct < NT; ++ct) {
        unsigned short* slab = Hs + (size_t)ct * slabR * 16;
#pragma unroll
        for (int r = 0; r < 4; ++r) {
            int row = qrow + r;
            if (row < n) slab[(size_t)row * 16 + m] = f2bf(acc[ct][r] * dv[r]);
        }
    }
}

// ---- aggregation: bucket x channel-slice, edge-parallel LDS accumulation ---
// block = (bucket, slice); slice = bid % NSL keeps one slab per XCD (L2-resident).
// out[d] = dinv[d]*(sum_nbr Hs[s] + Hs[d]) + bias, optional relu.

template<int NSL, bool RELU, bool BOUT>
__global__ __launch_bounds__(256) void agg_bucket_kernel(
    const unsigned short* __restrict__ Hs, size_t slabR,
    const float* __restrict__ bias, const float* __restrict__ dinv,
    const int* __restrict__ bbase, const int* __restrict__ ebuf,
    void* __restrict__ outv, int N) {
    __shared__ float acc[NPB][17];   // +1 pad: atomic bank spread
    int slice = blockIdx.x & (NSL - 1);
    int b = blockIdx.x / NSL;
    int t = threadIdx.x;
    const unsigned short* slab = Hs + (size_t)slice * slabR * 16;

    for (int i = t; i < NPB * 17; i += 256) ((float*)acc)[i] = 0.f;
    __syncthreads();

    int base = bbase[b], size = bbase[b + 1] - base;
    int half = t & 1;
    for (int i = t >> 1; i < size; i += 128) {
        int entry = ebuf[base + i];
        int s = entry >> NPB_SH, dl = entry & NPB_MASK;
        uint4 v = *(const uint4*)(slab + (size_t)s * 16 + half * 8);
        float* a = &acc[dl][half * 8];
        atomicAdd(&a[0], bf_lo(v.x)); atomicAdd(&a[1], bf_hi(v.x));
        atomicAdd(&a[2], bf_lo(v.y)); atomicAdd(&a[3], bf_hi(v.y));
        atomicAdd(&a[4], bf_lo(v.z)); atomicAdd(&a[5], bf_hi(v.z));
        atomicAdd(&a[6], bf_lo(v.w)); atomicAdd(&a[7], bf_hi(v.w));
    }
    __syncthreads();

    int node_base = b << NPB_SH;
    for (int i = t; i < NPB * 16; i += 256) {
        int nl = i >> 4, c = i & 15;
        int d = node_base + nl;
        if (d < N) {
            float self = bfu(slab[(size_t)d * 16 + c]);
            float r = dinv[d] * (acc[nl][c] + self) + bias[slice * 16 + c];
            if (RELU) r = fmaxf(r, 0.f);
            if (BOUT)
                ((unsigned short*)outv)[(size_t)slice * slabR * 16 + (size_t)d * 16 + c] = f2bf(r);
            else
                ((float*)outv)[(size_t)d * (NSL * 16) + slice * 16 + c] = r;
        }
    }
}

// ---- driver ----------------------------------------------------------------

extern "C" void kernel_launch(void* const* d_in, const int* in_sizes, int n_in,
                              void* d_out, int out_size, void* d_ws, size_t ws_size,
                              hipStream_t stream) {
    const float* x  = (const float*)d_in[0];
    const int*   ei = (const int*)d_in[1];
    const float* W1 = (const float*)d_in[2];
    const float* b1 = (const float*)d_in[3];
    const float* W2 = (const float*)d_in[4];
    const float* b2 = (const float*)d_in[5];
    float* out = (float*)d_out;

    int N = in_sizes[0] / IN_C;
    int E = in_sizes[1] / 2;
    const int* src = ei;
    const int* dst = ei + E;
    int B = (N + NPB - 1) >> NPB_SH;

    char* ws = (char*)d_ws;
    size_t off = 0;
    int*   bhist  = (int*)(ws + off);   off += (size_t)B * 4;
    int*   bbase  = (int*)(ws + off);   off += (size_t)(B + 1) * 4;
    int*   bcur   = (int*)(ws + off);   off += (size_t)B * 4;
    float* dinv   = (float*)(ws + off); off += (size_t)N * 4;
    off = (off + 15) & ~(size_t)15;
    int*   ebuf   = (int*)(ws + off);   off += (size_t)E * 4;
    off = (off + 15) & ~(size_t)15;
    unsigned short* H1  = (unsigned short*)(ws + off); off += (size_t)N * HID_C * 2;
    off = (off + 15) & ~(size_t)15;
    unsigned short* AG1 = (unsigned short*)(ws + off); off += (size_t)N * HID_C * 2;
    unsigned short* H2 = H1;   // H1 dead after agg1; reuse for layer-2 slabs

    hipMemsetAsync(bhist, 0, (size_t)B * 4, stream);

    int nblk = (E + B1_CHUNK - 1) / B1_CHUNK;
    hist_kernel<<<nblk, 256, 0, stream>>>(dst, bhist, E, B);
    scan_bucket_kernel<<<1, 1024, 0, stream>>>(bhist, bbase, bcur, B);
    bucket_kernel<<<nblk, 256, 0, stream>>>(src, dst, bcur, ebuf, E, B);
    dinv_bucket_kernel<<<B, 256, 0, stream>>>(ebuf, bbase, dinv, N);

    int mblk = (N + 63) / 64;
    mm_mfma_kernel<HID_C, float, false><<<mblk, 256, 0, stream>>>(x, W1, dinv, H1, N, (size_t)N);
    agg_bucket_kernel<HID_C / 16, true, true><<<B * (HID_C / 16), 256, 0, stream>>>(
        H1, (size_t)N, b1, dinv, bbase, ebuf, AG1, N);

    mm_mfma_kernel<OUT_C, unsigned short, true><<<mblk, 256, 0, stream>>>(AG1, W2, dinv, H2, N, (size_t)N);
    agg_bucket_kernel<OUT_C / 16, false, false><<<B * (OUT_C / 16), 256, 0, stream>>>(
        H2, (size_t)N, b2, dinv, bbase, ebuf, out, N);
}